// Round 6
// baseline (1701.376 us; speedup 1.0000x reference)
//
#include <hip/hip_runtime.h>

typedef unsigned short u16;
typedef unsigned int u32;

// ---------------------------------------------------------------------------
// Generic tiled GEMM: C[M=4096][N=1024] = A[4096][1024] * B[1024][1024] + bias
//   All fp32. BADDR 0: B is per-head stacked W[h][d][k] (h=c>>6,k=c&63)
//             BADDR 1: B is plain row-major [K][N]
//   OUTK  0: fp32 out, layout [bh][s][64]   (Q / V projections)
//   OUTK  1: fp32 out, layout [bh][64][s]   (K projection, transposed)
//   OUTK  2: fp32 out, row-major [r][1024]  (final output)
// ---------------------------------------------------------------------------
template<int BADDR, int OUTK>
__global__ __launch_bounds__(256) void gemm_kernel(
    const float* __restrict__ A,
    const float* __restrict__ Bm,
    const float* __restrict__ bias,
    float* __restrict__ Cf)
{
    const int KD = 1024;
    const int N  = 1024;

    __shared__ float As[16][64];  // [k][m]
    __shared__ float Bs[16][64];  // [k][n]

    const int tid = threadIdx.x;
    const int n0 = blockIdx.x * 64;
    const int m0 = blockIdx.y * 64;
    const int tx = tid & 15;
    const int ty = tid >> 4;

    float acc[4][4] = {};

    const int a_m  = tid >> 2;        // 0..63
    const int a_k4 = (tid & 3) * 4;   // 0,4,8,12
    const int b_k  = tid >> 4;        // 0..15
    const int b_n4 = (tid & 15) * 4;  // 0..60

    for (int k0 = 0; k0 < KD; k0 += 16) {
        __syncthreads();
        {
            float4 v = *(const float4*)(A + (long)(m0 + a_m) * KD + k0 + a_k4);
            As[a_k4 + 0][a_m] = v.x;
            As[a_k4 + 1][a_m] = v.y;
            As[a_k4 + 2][a_m] = v.z;
            As[a_k4 + 3][a_m] = v.w;
        }
        {
            long off;
            if constexpr (BADDR == 0) {
                const int h = n0 >> 6;  // N-tile (64) maps to exactly one head
                off = (long)h * (1024 * 64) + (long)(k0 + b_k) * 64 + b_n4;
            } else {
                off = (long)(k0 + b_k) * N + n0 + b_n4;
            }
            *(float4*)&Bs[b_k][b_n4] = *(const float4*)(Bm + off);
        }
        __syncthreads();

        #pragma unroll
        for (int kk = 0; kk < 16; ++kk) {
            float4 av = *(const float4*)&As[kk][ty * 4];
            float4 bv = *(const float4*)&Bs[kk][tx * 4];
            float a_[4] = {av.x, av.y, av.z, av.w};
            float b_[4] = {bv.x, bv.y, bv.z, bv.w};
            #pragma unroll
            for (int i = 0; i < 4; ++i)
                #pragma unroll
                for (int j = 0; j < 4; ++j)
                    acc[i][j] += a_[i] * b_[j];
        }
    }

    #pragma unroll
    for (int i = 0; i < 4; ++i) {
        const int r = m0 + ty * 4 + i;
        const int b = r >> 11;       // batch
        const int s = r & 2047;      // sequence
        #pragma unroll
        for (int j = 0; j < 4; ++j) {
            const int c = n0 + tx * 4 + j;
            const float v = acc[i][j] + bias[c];
            if constexpr (OUTK == 0) {
                const int h = c >> 6, k = c & 63;
                Cf[(((long)(b * 16 + h)) * 2048 + s) * 64 + k] = v;
            } else if constexpr (OUTK == 1) {
                const int h = c >> 6, k = c & 63;
                Cf[(((long)(b * 16 + h)) * 64 + k) * 2048 + s] = v;
            } else {
                Cf[(long)r * 1024 + c] = v;   // fp32 final output
            }
        }
    }
}

// ---------------------------------------------------------------------------
// Flash-style attention with online softmax.
//   qbuf: [BH][S][64] fp32, kbuf: [BH][64][S] fp32, vbuf: [BH][S][64] fp32
//   ctxbuf: [B][S][H*64] fp32
//   Block: 256 threads = 4 waves; 32 q-rows per block (8 per wave).
//   Reference math: attn = softmax(scores)/64/2 -> scale ctx by 1/(l*128).
// ---------------------------------------------------------------------------
__global__ __launch_bounds__(256) void attn_kernel(
    const float* __restrict__ qbuf,
    const float* __restrict__ kbuf,
    const float* __restrict__ vbuf,
    float* __restrict__ ctxbuf)
{
    const int S = 2048;
    __shared__ float qs_t[64][36];  // [d][r], padded
    __shared__ float ks[64][64];    // [d][t]
    __shared__ float vs[64][64];    // [t][d]
    __shared__ float ps[32][64];    // [r][t]

    const int tid  = threadIdx.x;
    const int lane = tid & 63;
    const int w    = tid >> 6;      // wave id 0..3
    const int bh   = blockIdx.y;    // 0..31
    const int b    = bh >> 4;
    const int h    = bh & 15;
    const int q0   = blockIdx.x * 32;

    const long qbase = ((long)bh * S + q0) * 64;
    const long kbase = (long)bh * 64 * S;
    const long vbase = (long)bh * S * 64;

    for (int i = tid; i < 32 * 64; i += 256) {
        qs_t[i & 63][i >> 6] = qbuf[qbase + i];
    }

    float4 m4[2], l4[2], acc[2];
    #pragma unroll
    for (int g = 0; g < 2; ++g) {
        m4[g]  = make_float4(-1e30f, -1e30f, -1e30f, -1e30f);
        l4[g]  = make_float4(0.f, 0.f, 0.f, 0.f);
        acc[g] = make_float4(0.f, 0.f, 0.f, 0.f);
    }

    const int rsub = lane >> 4;        // 0..3
    const int d4   = (lane & 15) * 4;  // 0..60

    for (int t0 = 0; t0 < S; t0 += 64) {
        __syncthreads();
        for (int ii = tid; ii < 1024; ii += 256) {
            const int d = ii >> 4, t4 = (ii & 15) * 4;
            *(float4*)&ks[d][t4] =
                *(const float4*)&kbuf[kbase + (long)d * S + t0 + t4];
        }
        {
            const float4* src = (const float4*)&vbuf[vbase + (long)t0 * 64];
            float4* dst = (float4*)&vs[0][0];
            for (int ii = tid; ii < 1024; ii += 256) dst[ii] = src[ii];
        }
        __syncthreads();

        float4 alpha4[2];
        // ---- score phase: lane = t ----
        #pragma unroll
        for (int g = 0; g < 2; ++g) {
            const int rbase = w * 8 + g * 4;
            float4 lg = make_float4(0.f, 0.f, 0.f, 0.f);
            #pragma unroll 8
            for (int d = 0; d < 64; ++d) {
                float4 qv = *(const float4*)&qs_t[d][rbase];
                float  kv = ks[d][lane];
                lg.x += qv.x * kv; lg.y += qv.y * kv;
                lg.z += qv.z * kv; lg.w += qv.w * kv;
            }
            float4 mt = lg;
            #pragma unroll
            for (int off = 32; off > 0; off >>= 1) {
                mt.x = fmaxf(mt.x, __shfl_xor(mt.x, off));
                mt.y = fmaxf(mt.y, __shfl_xor(mt.y, off));
                mt.z = fmaxf(mt.z, __shfl_xor(mt.z, off));
                mt.w = fmaxf(mt.w, __shfl_xor(mt.w, off));
            }
            float4 mn;
            mn.x = fmaxf(m4[g].x, mt.x); mn.y = fmaxf(m4[g].y, mt.y);
            mn.z = fmaxf(m4[g].z, mt.z); mn.w = fmaxf(m4[g].w, mt.w);
            float4 al;
            al.x = __expf(m4[g].x - mn.x); al.y = __expf(m4[g].y - mn.y);
            al.z = __expf(m4[g].z - mn.z); al.w = __expf(m4[g].w - mn.w);
            float4 p;
            p.x = __expf(lg.x - mn.x); p.y = __expf(lg.y - mn.y);
            p.z = __expf(lg.z - mn.z); p.w = __expf(lg.w - mn.w);
            float4 sm = p;
            #pragma unroll
            for (int off = 32; off > 0; off >>= 1) {
                sm.x += __shfl_xor(sm.x, off);
                sm.y += __shfl_xor(sm.y, off);
                sm.z += __shfl_xor(sm.z, off);
                sm.w += __shfl_xor(sm.w, off);
            }
            l4[g].x = al.x * l4[g].x + sm.x;
            l4[g].y = al.y * l4[g].y + sm.y;
            l4[g].z = al.z * l4[g].z + sm.z;
            l4[g].w = al.w * l4[g].w + sm.w;
            m4[g] = mn;
            alpha4[g] = al;
            ps[rbase + 0][lane] = p.x;
            ps[rbase + 1][lane] = p.y;
            ps[rbase + 2][lane] = p.z;
            ps[rbase + 3][lane] = p.w;
        }
        // ---- ctx phase ----
        #pragma unroll
        for (int g = 0; g < 2; ++g) {
            const int r = w * 8 + g * 4 + rsub;
            const float alpha = (rsub == 0) ? alpha4[g].x
                              : (rsub == 1) ? alpha4[g].y
                              : (rsub == 2) ? alpha4[g].z
                                            : alpha4[g].w;
            float4 a = acc[g];
            a.x *= alpha; a.y *= alpha; a.z *= alpha; a.w *= alpha;
            #pragma unroll 8
            for (int t = 0; t < 64; ++t) {
                const float p = ps[r][t];
                float4 vv = *(const float4*)&vs[t][d4];
                a.x += p * vv.x; a.y += p * vv.y;
                a.z += p * vv.z; a.w += p * vv.w;
            }
            acc[g] = a;
        }
    }

    // epilogue: scale by 1/(l*128), write fp32 ctx [b][s][h*64+d]
    #pragma unroll
    for (int g = 0; g < 2; ++g) {
        const int r = w * 8 + g * 4 + rsub;
        const float l = (rsub == 0) ? l4[g].x
                      : (rsub == 1) ? l4[g].y
                      : (rsub == 2) ? l4[g].z
                                    : l4[g].w;
        const float scale = 1.0f / (l * 128.0f);
        float4 a = acc[g];
        a.x *= scale; a.y *= scale; a.z *= scale; a.w *= scale;
        const long off = ((long)b * S + (q0 + r)) * 1024 + h * 64 + d4;
        *(float4*)&ctxbuf[off] = a;
    }
}

// ---------------------------------------------------------------------------
extern "C" void kernel_launch(void* const* d_in, const int* in_sizes, int n_in,
                              void* d_out, int out_size, void* d_ws, size_t ws_size,
                              hipStream_t stream) {
    (void)in_sizes; (void)n_in; (void)out_size; (void)ws_size;

    const float* Q  = (const float*)d_in[0];
    const float* K  = (const float*)d_in[1];
    const float* V  = (const float*)d_in[2];
    const float* Wq = (const float*)d_in[3];
    const float* bq = (const float*)d_in[4];
    const float* Wk = (const float*)d_in[5];
    const float* bk = (const float*)d_in[6];
    const float* Wv = (const float*)d_in[7];
    const float* bv = (const float*)d_in[8];
    const float* Wo = (const float*)d_in[9];
    const float* bo = (const float*)d_in[10];
    float* out = (float*)d_out;   // reference output dtype is float32

    float* ws = (float*)d_ws;
    const long PH = 2L * 16 * 2048 * 64;  // 4.19M floats per intermediate
    float* qb = ws;
    float* kb = ws + PH;
    float* vb = ws + 2 * PH;
    float* cb = ws + 3 * PH;

    dim3 gg(16, 64), bb(256);
    gemm_kernel<0, 0><<<gg, bb, 0, stream>>>(Q, Wq, bq, qb);
    gemm_kernel<0, 1><<<gg, bb, 0, stream>>>(K, Wk, bk, kb);
    gemm_kernel<0, 0><<<gg, bb, 0, stream>>>(V, Wv, bv, vb);

    attn_kernel<<<dim3(64, 32), bb, 0, stream>>>(qb, kb, vb, cb);

    gemm_kernel<1, 2><<<gg, bb, 0, stream>>>(cb, Wo, bo, out);
}

// Round 7
// 378.208 us; speedup vs baseline: 4.4985x; 4.4985x over previous
//
#include <hip/hip_runtime.h>

typedef unsigned short u16;
typedef unsigned int u32;
typedef __attribute__((ext_vector_type(8))) short bf16x8;
typedef __attribute__((ext_vector_type(4))) float f32x4;

__device__ __forceinline__ u16 f2b(float f) {
    union { float f; u32 u; } v; v.f = f;
    return (u16)((v.u + 0x7FFF + ((v.u >> 16) & 1)) >> 16);  // RNE
}

__device__ __forceinline__ void glds16(const u16* g, u16* l) {
    __builtin_amdgcn_global_load_lds(
        (const __attribute__((address_space(1))) void*)g,
        (__attribute__((address_space(3))) void*)l, 16, 0, 0);
}

// ---------------------------------------------------------------------------
// fp32 -> bf16 flat cast (n4 = element count / 4)
// ---------------------------------------------------------------------------
__global__ __launch_bounds__(256) void cast_bf16(
    const float* __restrict__ in, u16* __restrict__ out, int n4)
{
    int i = blockIdx.x * blockDim.x + threadIdx.x;
    const int stride = gridDim.x * blockDim.x;
    for (; i < n4; i += stride) {
        float4 v = ((const float4*)in)[i];
        ushort4 o;
        o.x = f2b(v.x); o.y = f2b(v.y); o.z = f2b(v.z); o.w = f2b(v.w);
        ((ushort4*)out)[i] = o;
    }
}

// ---------------------------------------------------------------------------
// fp32 [mat][R][C] -> bf16 [mat][C][R] transpose-cast, 64x64 LDS tiles.
// ---------------------------------------------------------------------------
__global__ __launch_bounds__(256) void tcast(
    const float* __restrict__ in, u16* __restrict__ out, int R, int C)
{
    __shared__ float t[64][68];
    const long mb = (long)blockIdx.z * R * C;
    const int r0 = blockIdx.x * 64, c0 = blockIdx.y * 64;
    const int tid = threadIdx.x;
    const int rr = tid >> 4, c4 = (tid & 15) * 4;

    #pragma unroll
    for (int p = 0; p < 4; ++p) {
        float4 v = *(const float4*)(in + mb + (long)(r0 + p * 16 + rr) * C + c0 + c4);
        *(float4*)&t[p * 16 + rr][c4] = v;   // 272B row stride (16B-aligned)
    }
    __syncthreads();
    #pragma unroll
    for (int p = 0; p < 4; ++p) {
        const int oc = p * 16 + rr;          // output row (C-dim index)
        const int r4 = (tid & 15) * 4;
        ushort4 o;
        o.x = f2b(t[r4 + 0][oc]); o.y = f2b(t[r4 + 1][oc]);
        o.z = f2b(t[r4 + 2][oc]); o.w = f2b(t[r4 + 3][oc]);
        *(ushort4*)(out + mb + (long)(c0 + oc) * R + r0 + r4) = o;
    }
}

// ---------------------------------------------------------------------------
// bf16 MFMA GEMM: C[4096][1024] = A[4096][1024] @ BT[1024 n][1024 k]^T + bias
//   128x128 tile, 4 waves (2x2), each wave 64x64 = 4x4 subtiles of 16x16.
//   global_load_lds width-16 staging; frag layouts per m89/m92/m120.
//   OUTK 0: bf16 out [bh][s][64]   (QW / KW)
//   OUTK 1: bf16 out [bh][64 k][2048 s]  (VW, d-major)
//   OUTK 2: fp32 out row-major [m][1024]  (final output)
// ---------------------------------------------------------------------------
template<int OUTK>
__global__ __launch_bounds__(256) void gemm_bt(
    const u16* __restrict__ A, const u16* __restrict__ BT,
    const float* __restrict__ bias,
    u16* __restrict__ Cu, float* __restrict__ Cf)
{
    __shared__ u16 As[128 * 64];   // [m][k-chunk], 16 KB
    __shared__ u16 Bs[128 * 64];   // [n][k-chunk], 16 KB

    const int tid = threadIdx.x, lane = tid & 63, w = tid >> 6;
    const int m0 = blockIdx.y * 128, n0 = blockIdx.x * 128;
    const int wm = (w >> 1) * 64, wn = (w & 1) * 64;
    const int fr = lane & 15, quad = lane >> 4;

    f32x4 acc[4][4];
    const f32x4 zero = {0.f, 0.f, 0.f, 0.f};
    #pragma unroll
    for (int mi = 0; mi < 4; ++mi)
        #pragma unroll
        for (int ni = 0; ni < 4; ++ni) acc[mi][ni] = zero;

    const int srow = lane >> 3;    // 0..7 row-in-group
    const int schk = lane & 7;     // 16B chunk
    const long ga = (long)(m0 + srow) * 1024 + schk * 8;
    const long gb = (long)(n0 + srow) * 1024 + schk * 8;

    for (int k0 = 0; k0 < 1024; k0 += 64) {
        __syncthreads();
        #pragma unroll
        for (int i2 = 0; i2 < 4; ++i2) {
            const int i = w * 4 + i2;
            glds16(A + ga + (long)i * 8 * 1024 + k0, &As[i * 512]);
            glds16(BT + gb + (long)i * 8 * 1024 + k0, &Bs[i * 512]);
        }
        __syncthreads();
        #pragma unroll
        for (int kc = 0; kc < 2; ++kc) {
            bf16x8 af[4], bf[4];
            #pragma unroll
            for (int mi = 0; mi < 4; ++mi)
                af[mi] = *(const bf16x8*)&As[(wm + mi * 16 + fr) * 64 + kc * 32 + quad * 8];
            #pragma unroll
            for (int ni = 0; ni < 4; ++ni)
                bf[ni] = *(const bf16x8*)&Bs[(wn + ni * 16 + fr) * 64 + kc * 32 + quad * 8];
            #pragma unroll
            for (int mi = 0; mi < 4; ++mi)
                #pragma unroll
                for (int ni = 0; ni < 4; ++ni)
                    acc[mi][ni] = __builtin_amdgcn_mfma_f32_16x16x32_bf16(
                        af[mi], bf[ni], acc[mi][ni], 0, 0, 0);
        }
    }

    // epilogue: C/D layout col=lane&15, row=quad*4+reg
    #pragma unroll
    for (int mi = 0; mi < 4; ++mi) {
        #pragma unroll
        for (int ni = 0; ni < 4; ++ni) {
            #pragma unroll
            for (int r = 0; r < 4; ++r) {
                const int m = m0 + wm + mi * 16 + quad * 4 + r;
                const int c = n0 + wn + ni * 16 + fr;
                const float v = acc[mi][ni][r] + bias[c];
                if constexpr (OUTK == 2) {
                    Cf[(long)m * 1024 + c] = v;
                } else {
                    const int b = m >> 11, s = m & 2047, h = c >> 6, k = c & 63;
                    if constexpr (OUTK == 0)
                        Cu[((long)(b * 16 + h) * 2048 + s) * 64 + k] = f2b(v);
                    else
                        Cu[((long)(b * 16 + h) * 64 + k) * 2048 + s] = f2b(v);
                }
            }
        }
    }
}

// ---------------------------------------------------------------------------
// MFMA flash attention. QW/KW: [bh][2048][64] bf16; VW: [bh][64][2048] bf16.
//   Block = 4 waves; wave w owns q-rows q0+w*16 .. +16. t-tiles of 64.
//   attn = softmax(scores)/64/2 -> ctx scaled by 1/(l*128). ctx bf16 out.
// ---------------------------------------------------------------------------
__global__ __launch_bounds__(256) void attn_mfma(
    const u16* __restrict__ QW, const u16* __restrict__ KW,
    const u16* __restrict__ VW, u16* __restrict__ ctxb)
{
    __shared__ u16 kt[64 * 64];      // [t][k]  8 KB
    __shared__ u16 vt[64 * 64];      // [d][t]  8 KB
    __shared__ u16 ps[4][16 * 64];   // per-wave P [q][t] 2 KB each

    const int tid = threadIdx.x, lane = tid & 63, w = tid >> 6;
    const int bh = blockIdx.y, b = bh >> 4, h = bh & 15;
    const int q0 = blockIdx.x * 64;
    const int fr = lane & 15, quad = lane >> 4;

    // Q A-frags (registers, whole kernel): A[m=lane&15][k=quad*8+j]
    const u16* qp = QW + ((long)bh * 2048 + q0 + w * 16 + fr) * 64;
    const bf16x8 aQ0 = *(const bf16x8*)(qp + quad * 8);
    const bf16x8 aQ1 = *(const bf16x8*)(qp + 32 + quad * 8);

    f32x4 acc[4];
    const f32x4 zero = {0.f, 0.f, 0.f, 0.f};
    float m_run[4], l_run[4];
    #pragma unroll
    for (int d = 0; d < 4; ++d) acc[d] = zero;
    #pragma unroll
    for (int r = 0; r < 4; ++r) { m_run[r] = -1e30f; l_run[r] = 0.f; }

    const int srow = lane >> 3, schk = lane & 7;
    const long kg = (long)bh * (2048 * 64) + (long)srow * 64 + schk * 8;
    const long vg = (long)bh * (64 * 2048) + (long)srow * 2048 + schk * 8;

    for (int t0 = 0; t0 < 2048; t0 += 64) {
        __syncthreads();
        #pragma unroll
        for (int i2 = 0; i2 < 2; ++i2) {
            const int i = w * 2 + i2;
            glds16(KW + kg + (long)t0 * 64 + (long)i * 8 * 64, &kt[i * 512]);
            glds16(VW + vg + t0 + (long)i * 8 * 2048, &vt[i * 512]);
        }
        __syncthreads();

        // ---- QK^T: 4 t-subtiles of 16 ----
        f32x4 sc[4];
        #pragma unroll
        for (int sub = 0; sub < 4; ++sub) {
            bf16x8 b0 = *(const bf16x8*)&kt[(sub * 16 + fr) * 64 + quad * 8];
            bf16x8 b1 = *(const bf16x8*)&kt[(sub * 16 + fr) * 64 + 32 + quad * 8];
            f32x4 z = __builtin_amdgcn_mfma_f32_16x16x32_bf16(aQ0, b0, zero, 0, 0, 0);
            sc[sub]  = __builtin_amdgcn_mfma_f32_16x16x32_bf16(aQ1, b1, z, 0, 0, 0);
        }

        // ---- online softmax (row = quad*4+r, stats shared by quad's 16 lanes)
        float alpha[4];
        #pragma unroll
        for (int r = 0; r < 4; ++r) {
            float mx = fmaxf(fmaxf(sc[0][r], sc[1][r]), fmaxf(sc[2][r], sc[3][r]));
            mx = fmaxf(mx, __shfl_xor(mx, 1));
            mx = fmaxf(mx, __shfl_xor(mx, 2));
            mx = fmaxf(mx, __shfl_xor(mx, 4));
            mx = fmaxf(mx, __shfl_xor(mx, 8));
            const float mn = fmaxf(m_run[r], mx);
            alpha[r] = __expf(m_run[r] - mn);
            m_run[r] = mn;
            float s0 = 0.f;
            #pragma unroll
            for (int sub = 0; sub < 4; ++sub) {
                sc[sub][r] = __expf(sc[sub][r] - mn);
                s0 += sc[sub][r];
            }
            s0 += __shfl_xor(s0, 1);
            s0 += __shfl_xor(s0, 2);
            s0 += __shfl_xor(s0, 4);
            s0 += __shfl_xor(s0, 8);
            l_run[r] = alpha[r] * l_run[r] + s0;
        }
        #pragma unroll
        for (int d = 0; d < 4; ++d) {
            acc[d][0] *= alpha[0]; acc[d][1] *= alpha[1];
            acc[d][2] *= alpha[2]; acc[d][3] *= alpha[3];
        }

        // ---- P: C-layout -> LDS -> A-layout (wave-private region) ----
        u16* pw = ps[w];
        #pragma unroll
        for (int sub = 0; sub < 4; ++sub)
            #pragma unroll
            for (int r = 0; r < 4; ++r)
                pw[(quad * 4 + r) * 64 + sub * 16 + fr] = f2b(sc[sub][r]);
        __asm__ volatile("s_waitcnt lgkmcnt(0)" ::: "memory");
        const bf16x8 aP0 = *(const bf16x8*)&pw[fr * 64 + quad * 8];
        const bf16x8 aP1 = *(const bf16x8*)&pw[fr * 64 + 32 + quad * 8];

        // ---- PV: 4 d-subtiles ----
        #pragma unroll
        for (int d = 0; d < 4; ++d) {
            bf16x8 b0 = *(const bf16x8*)&vt[(d * 16 + fr) * 64 + quad * 8];
            bf16x8 b1 = *(const bf16x8*)&vt[(d * 16 + fr) * 64 + 32 + quad * 8];
            acc[d] = __builtin_amdgcn_mfma_f32_16x16x32_bf16(aP0, b0, acc[d], 0, 0, 0);
            acc[d] = __builtin_amdgcn_mfma_f32_16x16x32_bf16(aP1, b1, acc[d], 0, 0, 0);
        }
    }

    // epilogue: row = q0+w*16+quad*4+r, col d = dsub*16+fr
    #pragma unroll
    for (int r = 0; r < 4; ++r) {
        const float s = 1.0f / (l_run[r] * 128.0f);
        const long row = (long)b * 2048 + q0 + w * 16 + quad * 4 + r;
        #pragma unroll
        for (int d = 0; d < 4; ++d)
            ctxb[row * 1024 + h * 64 + d * 16 + fr] = f2b(acc[d][r] * s);
    }
}

// ---------------------------------------------------------------------------
extern "C" void kernel_launch(void* const* d_in, const int* in_sizes, int n_in,
                              void* d_out, int out_size, void* d_ws, size_t ws_size,
                              hipStream_t stream) {
    (void)in_sizes; (void)n_in; (void)out_size; (void)ws_size;

    const float* Q  = (const float*)d_in[0];
    const float* K  = (const float*)d_in[1];
    const float* V  = (const float*)d_in[2];
    const float* Wq = (const float*)d_in[3];
    const float* bq = (const float*)d_in[4];
    const float* Wk = (const float*)d_in[5];
    const float* bk = (const float*)d_in[6];
    const float* Wv = (const float*)d_in[7];
    const float* bv = (const float*)d_in[8];
    const float* Wo = (const float*)d_in[9];
    const float* bo = (const float*)d_in[10];
    float* out = (float*)d_out;

    u16* ws  = (u16*)d_ws;                // 64 MB total (<= proven 67 MB)
    u16* Qb  = ws;                        // 4096x1024
    u16* Kb  = Qb  + 4194304;
    u16* Vb  = Kb  + 4194304;
    u16* WqT = Vb  + 4194304;             // [16][64][1024]
    u16* WkT = WqT + 1048576;
    u16* WvT = WkT + 1048576;
    u16* WoT = WvT + 1048576;             // [1024][1024]
    u16* QWb = WoT + 1048576;             // [32][2048][64]
    u16* KWb = QWb + 4194304;             // [32][2048][64]
    u16* VWb = KWb + 4194304;             // [32][64][2048]
    u16* ctx = VWb + 4194304;             // [4096][1024]

    cast_bf16<<<1024, 256, 0, stream>>>(Q, Qb, 1048576);
    cast_bf16<<<1024, 256, 0, stream>>>(K, Kb, 1048576);
    cast_bf16<<<1024, 256, 0, stream>>>(V, Vb, 1048576);
    tcast<<<dim3(16, 1, 16), 256, 0, stream>>>(Wq, WqT, 1024, 64);
    tcast<<<dim3(16, 1, 16), 256, 0, stream>>>(Wk, WkT, 1024, 64);
    tcast<<<dim3(16, 1, 16), 256, 0, stream>>>(Wv, WvT, 1024, 64);
    tcast<<<dim3(16, 16, 1), 256, 0, stream>>>(Wo, WoT, 1024, 1024);

    gemm_bt<0><<<dim3(8, 32), 256, 0, stream>>>(Qb, WqT, bq, QWb, nullptr);
    gemm_bt<0><<<dim3(8, 32), 256, 0, stream>>>(Kb, WkT, bk, KWb, nullptr);
    gemm_bt<1><<<dim3(8, 32), 256, 0, stream>>>(Vb, WvT, bv, VWb, nullptr);

    attn_mfma<<<dim3(32, 32), 256, 0, stream>>>(QWb, KWb, VWb, ctx);

    gemm_bt<2><<<dim3(8, 32), 256, 0, stream>>>(ctx, WoT, bo, nullptr, out);
}

// Round 8
// 263.374 us; speedup vs baseline: 6.4599x; 1.4360x over previous
//
#include <hip/hip_runtime.h>

typedef unsigned short u16;
typedef unsigned int u32;
typedef __attribute__((ext_vector_type(8))) short bf16x8;
typedef __attribute__((ext_vector_type(4))) float f32x4;

__device__ __forceinline__ u16 f2b(float f) {
    union { float f; u32 u; } v; v.f = f;
    return (u16)((v.u + 0x7FFF + ((v.u >> 16) & 1)) >> 16);  // RNE
}

__device__ __forceinline__ void glds16(const u16* g, u16* l) {
    __builtin_amdgcn_global_load_lds(
        (const __attribute__((address_space(1))) void*)g,
        (__attribute__((address_space(3))) void*)l, 16, 0, 0);
}

// ---------------------------------------------------------------------------
// fp32 -> bf16 flat casts for Q, K, V (grid.z selects input). n4 = 1048576.
// ---------------------------------------------------------------------------
__global__ __launch_bounds__(256) void cast3(
    const float* __restrict__ Q, const float* __restrict__ K,
    const float* __restrict__ V,
    u16* __restrict__ Qb, u16* __restrict__ Kb, u16* __restrict__ Vb)
{
    const float* in = (blockIdx.z == 0) ? Q : (blockIdx.z == 1) ? K : V;
    u16* out = (blockIdx.z == 0) ? Qb : (blockIdx.z == 1) ? Kb : Vb;
    const int n4 = 1048576;
    const int stride = gridDim.x * 256;
    for (int i = blockIdx.x * 256 + threadIdx.x; i < n4; i += stride) {
        float4 v = ((const float4*)in)[i];
        ushort4 o;
        o.x = f2b(v.x); o.y = f2b(v.y); o.z = f2b(v.z); o.w = f2b(v.w);
        ((ushort4*)out)[i] = o;
    }
}

// ---------------------------------------------------------------------------
// Per-head weight transpose-cast: fp32 [16][1024][64] -> bf16 [16][64][1024].
// grid (16, 1, 48): z>>4 selects Wq/Wk/Wv, z&15 = head.
// ---------------------------------------------------------------------------
__global__ __launch_bounds__(256) void tcastW(
    const float* __restrict__ Wq, const float* __restrict__ Wk,
    const float* __restrict__ Wv,
    u16* __restrict__ WqT, u16* __restrict__ WkT, u16* __restrict__ WvT)
{
    __shared__ float t[64][68];
    const int sel = blockIdx.z >> 4, hz = blockIdx.z & 15;
    const float* in = (sel == 0) ? Wq : (sel == 1) ? Wk : Wv;
    u16* out = (sel == 0) ? WqT : (sel == 1) ? WkT : WvT;
    const long mb = (long)hz * 65536;
    const int r0 = blockIdx.x * 64;
    const int tid = threadIdx.x;
    const int rr = tid >> 4, c4 = (tid & 15) * 4;

    #pragma unroll
    for (int p = 0; p < 4; ++p) {
        float4 v = *(const float4*)(in + mb + (long)(r0 + p * 16 + rr) * 64 + c4);
        *(float4*)&t[p * 16 + rr][c4] = v;
    }
    __syncthreads();
    #pragma unroll
    for (int p = 0; p < 4; ++p) {
        const int oc = p * 16 + rr;          // output row (col of W, 0..63)
        const int r4 = (tid & 15) * 4;
        ushort4 o;
        o.x = f2b(t[r4 + 0][oc]); o.y = f2b(t[r4 + 1][oc]);
        o.z = f2b(t[r4 + 2][oc]); o.w = f2b(t[r4 + 3][oc]);
        *(ushort4*)(out + mb + (long)oc * 1024 + r0 + r4) = o;
    }
}

// ---------------------------------------------------------------------------
// Wo transpose-cast: fp32 [1024][1024] -> bf16 [1024][1024]^T. grid (16,16).
// ---------------------------------------------------------------------------
__global__ __launch_bounds__(256) void tcastWo(
    const float* __restrict__ in, u16* __restrict__ out)
{
    __shared__ float t[64][68];
    const int r0 = blockIdx.x * 64, c0 = blockIdx.y * 64;
    const int tid = threadIdx.x;
    const int rr = tid >> 4, c4 = (tid & 15) * 4;

    #pragma unroll
    for (int p = 0; p < 4; ++p) {
        float4 v = *(const float4*)(in + (long)(r0 + p * 16 + rr) * 1024 + c0 + c4);
        *(float4*)&t[p * 16 + rr][c4] = v;
    }
    __syncthreads();
    #pragma unroll
    for (int p = 0; p < 4; ++p) {
        const int oc = p * 16 + rr;
        const int r4 = (tid & 15) * 4;
        ushort4 o;
        o.x = f2b(t[r4 + 0][oc]); o.y = f2b(t[r4 + 1][oc]);
        o.z = f2b(t[r4 + 2][oc]); o.w = f2b(t[r4 + 3][oc]);
        *(ushort4*)(out + (long)(c0 + oc) * 1024 + r0 + r4) = o;
    }
}

// ---------------------------------------------------------------------------
// GEMM body macro pieces shared by proj3 / gemm_out.
// 128x128 tile, 4 waves 2x2, XOR-swizzled LDS (chunk stored at chunk^(row&7)).
// ---------------------------------------------------------------------------
#define GEMM_CORE(A_, BT_)                                                     \
    __shared__ u16 As[128 * 64];                                               \
    __shared__ u16 Bs[128 * 64];                                               \
    const int tid = threadIdx.x, lane = tid & 63, w = tid >> 6;                \
    const int m0 = blockIdx.y * 128, n0 = blockIdx.x * 128;                    \
    const int wm = (w >> 1) * 64, wn = (w & 1) * 64;                           \
    const int fr = lane & 15, quad = lane >> 4;                                \
    f32x4 acc[4][4];                                                           \
    const f32x4 zero = {0.f, 0.f, 0.f, 0.f};                                   \
    _Pragma("unroll")                                                          \
    for (int mi = 0; mi < 4; ++mi)                                             \
        _Pragma("unroll")                                                      \
        for (int ni = 0; ni < 4; ++ni) acc[mi][ni] = zero;                     \
    const int srow = lane >> 3;                                                \
    const int schk = (lane & 7) ^ (srow & 7);   /* swizzled source chunk */    \
    const long ga = (long)(m0 + srow) * 1024 + schk * 8;                       \
    const long gb = (long)(n0 + srow) * 1024 + schk * 8;                       \
    const int f7 = fr & 7;                                                     \
    for (int k0 = 0; k0 < 1024; k0 += 64) {                                    \
        __syncthreads();                                                       \
        _Pragma("unroll")                                                      \
        for (int i2 = 0; i2 < 4; ++i2) {                                       \
            const int i = w * 4 + i2;                                          \
            glds16(A_ + ga + (long)i * 8 * 1024 + k0, &As[i * 512]);           \
            glds16(BT_ + gb + (long)i * 8 * 1024 + k0, &Bs[i * 512]);          \
        }                                                                      \
        __syncthreads();                                                       \
        _Pragma("unroll")                                                      \
        for (int kc = 0; kc < 2; ++kc) {                                       \
            const int pos = ((kc * 4 + quad) ^ f7) * 8;                        \
            bf16x8 af[4], bfr[4];                                              \
            _Pragma("unroll")                                                  \
            for (int mi = 0; mi < 4; ++mi)                                     \
                af[mi] = *(const bf16x8*)&As[(wm + mi * 16 + fr) * 64 + pos];  \
            _Pragma("unroll")                                                  \
            for (int ni = 0; ni < 4; ++ni)                                     \
                bfr[ni] = *(const bf16x8*)&Bs[(wn + ni * 16 + fr) * 64 + pos]; \
            _Pragma("unroll")                                                  \
            for (int mi = 0; mi < 4; ++mi)                                     \
                _Pragma("unroll")                                              \
                for (int ni = 0; ni < 4; ++ni)                                 \
                    acc[mi][ni] = __builtin_amdgcn_mfma_f32_16x16x32_bf16(     \
                        af[mi], bfr[ni], acc[mi][ni], 0, 0, 0);                \
        }                                                                      \
    }

// Projections (z: 0=Q, 1=K, 2=V). OUT: z<2 -> [bh][s][64]; z==2 -> [bh][64][s]
__global__ __launch_bounds__(256) void proj3(
    const u16* __restrict__ Qb, const u16* __restrict__ Kb,
    const u16* __restrict__ Vb,
    const u16* __restrict__ WqT, const u16* __restrict__ WkT,
    const u16* __restrict__ WvT,
    const float* __restrict__ bq, const float* __restrict__ bk,
    const float* __restrict__ bv,
    u16* __restrict__ QWb, u16* __restrict__ KWb, u16* __restrict__ VWb)
{
    const int z = blockIdx.z;
    const u16* A  = (z == 0) ? Qb : (z == 1) ? Kb : Vb;
    const u16* BT = (z == 0) ? WqT : (z == 1) ? WkT : WvT;
    const float* bias = (z == 0) ? bq : (z == 1) ? bk : bv;
    u16* Cu = (z == 0) ? QWb : (z == 1) ? KWb : VWb;

    GEMM_CORE(A, BT)

    #pragma unroll
    for (int mi = 0; mi < 4; ++mi) {
        #pragma unroll
        for (int ni = 0; ni < 4; ++ni) {
            #pragma unroll
            for (int r = 0; r < 4; ++r) {
                const int m = m0 + wm + mi * 16 + quad * 4 + r;
                const int c = n0 + wn + ni * 16 + fr;
                const float v = acc[mi][ni][r] + bias[c];
                const int b = m >> 11, s = m & 2047, h = c >> 6, k = c & 63;
                if (z != 2)
                    Cu[((long)(b * 16 + h) * 2048 + s) * 64 + k] = f2b(v);
                else
                    Cu[((long)(b * 16 + h) * 64 + k) * 2048 + s] = f2b(v);
            }
        }
    }
}

// Output projection: fp32 out = ctx(bf16) @ WoT^T + bo
__global__ __launch_bounds__(256) void gemm_out(
    const u16* __restrict__ A, const u16* __restrict__ BT,
    const float* __restrict__ bias, float* __restrict__ Cf)
{
    GEMM_CORE(A, BT)

    #pragma unroll
    for (int mi = 0; mi < 4; ++mi) {
        #pragma unroll
        for (int ni = 0; ni < 4; ++ni) {
            #pragma unroll
            for (int r = 0; r < 4; ++r) {
                const int m = m0 + wm + mi * 16 + quad * 4 + r;
                const int c = n0 + wn + ni * 16 + fr;
                Cf[(long)m * 1024 + c] = acc[mi][ni][r] + bias[c];
            }
        }
    }
}

// ---------------------------------------------------------------------------
// MFMA flash attention v2. QW/KW: [bh][2048][64]; VW: [bh][64][2048] (bf16).
//   Block = 4 waves, 128 q rows (32 per wave as 2 sets of 16). t-tiles of 64.
//   Non-centered softmax: p = exp(s); l accumulated via MFMA with ones-B.
//   attn = softmax/64/2 -> ctx scaled by 1/(l*128). XOR-swizzled kt/vt.
// ---------------------------------------------------------------------------
__global__ __launch_bounds__(256) void attn_mfma(
    const u16* __restrict__ QW, const u16* __restrict__ KW,
    const u16* __restrict__ VW, u16* __restrict__ ctxb)
{
    __shared__ u16 kt[64 * 64];      // [t][k] swizzled, 8 KB
    __shared__ u16 vt[64 * 64];      // [d][t] swizzled, 8 KB
    __shared__ u16 ps[4][32 * 72];   // per-wave P [q][t], stride 72, 18 KB

    const int tid = threadIdx.x, lane = tid & 63, w = tid >> 6;
    const int bh = blockIdx.y, b = bh >> 4, h = bh & 15;
    const int q0 = blockIdx.x * 128;
    const int fr = lane & 15, quad = lane >> 4;
    const int f7 = fr & 7;

    // Q A-frags: 2 q-sets of 16 rows
    bf16x8 aQ[2][2];
    #pragma unroll
    for (int s = 0; s < 2; ++s) {
        const u16* qp = QW + ((long)bh * 2048 + q0 + w * 32 + s * 16 + fr) * 64;
        aQ[s][0] = *(const bf16x8*)(qp + quad * 8);
        aQ[s][1] = *(const bf16x8*)(qp + 32 + quad * 8);
    }

    const f32x4 zero = {0.f, 0.f, 0.f, 0.f};
    f32x4 acc[2][4], lac[2];
    #pragma unroll
    for (int s = 0; s < 2; ++s) {
        lac[s] = zero;
        #pragma unroll
        for (int d = 0; d < 4; ++d) acc[s][d] = zero;
    }
    bf16x8 bones;
    #pragma unroll
    for (int j = 0; j < 8; ++j) bones[j] = (short)0x3F80;  // bf16 1.0

    const int srow = lane >> 3;
    const int schk = (lane & 7) ^ (srow & 7);   // swizzled source chunk
    const long kgb = (long)bh * (2048 * 64);
    const long vgb = (long)bh * (64 * 2048);

    for (int t0 = 0; t0 < 2048; t0 += 64) {
        __syncthreads();
        #pragma unroll
        for (int i2 = 0; i2 < 2; ++i2) {
            const int i = w * 2 + i2;
            glds16(KW + kgb + (long)(t0 + i * 8 + srow) * 64 + schk * 8, &kt[i * 512]);
            glds16(VW + vgb + (long)(i * 8 + srow) * 2048 + t0 + schk * 8, &vt[i * 512]);
        }
        __syncthreads();

        const int pos0 = (quad ^ f7) * 8;      // swizzled chunk {quad}
        const int pos1 = pos0 ^ 32;            // swizzled chunk {quad+4}

        // ---- QK^T + exp + P->LDS for both q-sets ----
        #pragma unroll
        for (int s = 0; s < 2; ++s) {
            f32x4 sc[4];
            #pragma unroll
            for (int sub = 0; sub < 4; ++sub) {
                const int row = (sub * 16 + fr) * 64;
                bf16x8 b0 = *(const bf16x8*)&kt[row + pos0];
                bf16x8 b1 = *(const bf16x8*)&kt[row + pos1];
                f32x4 z = __builtin_amdgcn_mfma_f32_16x16x32_bf16(aQ[s][0], b0, zero, 0, 0, 0);
                sc[sub]  = __builtin_amdgcn_mfma_f32_16x16x32_bf16(aQ[s][1], b1, z, 0, 0, 0);
            }
            u16* pw = ps[w] + s * 16 * 72;
            #pragma unroll
            for (int sub = 0; sub < 4; ++sub)
                #pragma unroll
                for (int r = 0; r < 4; ++r)
                    pw[(quad * 4 + r) * 72 + sub * 16 + fr] = f2b(__expf(sc[sub][r]));
        }
        __asm__ volatile("s_waitcnt lgkmcnt(0)" ::: "memory");

        // ---- l (ones-MFMA) + PV for both q-sets ----
        #pragma unroll
        for (int s = 0; s < 2; ++s) {
            const u16* pw = ps[w] + s * 16 * 72;
            const bf16x8 aP0 = *(const bf16x8*)&pw[fr * 72 + quad * 8];
            const bf16x8 aP1 = *(const bf16x8*)&pw[fr * 72 + 32 + quad * 8];
            lac[s] = __builtin_amdgcn_mfma_f32_16x16x32_bf16(aP0, bones, lac[s], 0, 0, 0);
            lac[s] = __builtin_amdgcn_mfma_f32_16x16x32_bf16(aP1, bones, lac[s], 0, 0, 0);
            #pragma unroll
            for (int d = 0; d < 4; ++d) {
                const int row = (d * 16 + fr) * 64;
                bf16x8 v0 = *(const bf16x8*)&vt[row + pos0];
                bf16x8 v1 = *(const bf16x8*)&vt[row + pos1];
                acc[s][d] = __builtin_amdgcn_mfma_f32_16x16x32_bf16(aP0, v0, acc[s][d], 0, 0, 0);
                acc[s][d] = __builtin_amdgcn_mfma_f32_16x16x32_bf16(aP1, v1, acc[s][d], 0, 0, 0);
            }
        }
    }

    // epilogue: ctx = acc/(l*128), row = q0 + w*32 + s*16 + quad*4 + r
    #pragma unroll
    for (int s = 0; s < 2; ++s) {
        #pragma unroll
        for (int r = 0; r < 4; ++r) {
            const float scl = 1.0f / (lac[s][r] * 128.0f);
            const long row = (long)b * 2048 + q0 + w * 32 + s * 16 + quad * 4 + r;
            #pragma unroll
            for (int d = 0; d < 4; ++d)
                ctxb[row * 1024 + h * 64 + d * 16 + fr] = f2b(acc[s][d][r] * scl);
        }
    }
}

// ---------------------------------------------------------------------------
extern "C" void kernel_launch(void* const* d_in, const int* in_sizes, int n_in,
                              void* d_out, int out_size, void* d_ws, size_t ws_size,
                              hipStream_t stream) {
    (void)in_sizes; (void)n_in; (void)out_size; (void)ws_size;

    const float* Q  = (const float*)d_in[0];
    const float* K  = (const float*)d_in[1];
    const float* V  = (const float*)d_in[2];
    const float* Wq = (const float*)d_in[3];
    const float* bq = (const float*)d_in[4];
    const float* Wk = (const float*)d_in[5];
    const float* bk = (const float*)d_in[6];
    const float* Wv = (const float*)d_in[7];
    const float* bv = (const float*)d_in[8];
    const float* Wo = (const float*)d_in[9];
    const float* bo = (const float*)d_in[10];
    float* out = (float*)d_out;

    u16* ws  = (u16*)d_ws;                // 64 MB total
    u16* Qb  = ws;                        // 4096x1024
    u16* Kb  = Qb  + 4194304;
    u16* Vb  = Kb  + 4194304;
    u16* WqT = Vb  + 4194304;             // [16][64][1024]
    u16* WkT = WqT + 1048576;
    u16* WvT = WkT + 1048576;
    u16* WoT = WvT + 1048576;             // [1024][1024]
    u16* QWb = WoT + 1048576;             // [32][2048][64]
    u16* KWb = QWb + 4194304;             // [32][2048][64]
    u16* VWb = KWb + 4194304;             // [32][64][2048]
    u16* ctx = VWb + 4194304;             // [4096][1024]

    cast3<<<dim3(1024, 1, 3), 256, 0, stream>>>(Q, K, V, Qb, Kb, Vb);
    tcastW<<<dim3(16, 1, 48), 256, 0, stream>>>(Wq, Wk, Wv, WqT, WkT, WvT);
    tcastWo<<<dim3(16, 16), 256, 0, stream>>>(Wo, WoT);

    proj3<<<dim3(8, 32, 3), 256, 0, stream>>>(Qb, Kb, Vb, WqT, WkT, WvT,
                                              bq, bk, bv, QWb, KWb, VWb);

    attn_mfma<<<dim3(16, 32), 256, 0, stream>>>(QWb, KWb, VWb, ctx);

    gemm_out<<<dim3(8, 32), 256, 0, stream>>>(ctx, WoT, bo, out);
}